// Round 1
// baseline (190.027 us; speedup 1.0000x reference)
//
#include <hip/hip_runtime.h>

#define N     4096
#define FIN   256
#define CC    256   // HEADS * F_OUT
#define HEADS 4
#define FOUT  64
#define XPITCH 266  // FIN+10 shorts = 133 dwords (odd) -> conflict-free
#define HPITCH 74   // 37 dwords (odd)

typedef __attribute__((ext_vector_type(8))) short bf16x8;
typedef __attribute__((ext_vector_type(4))) float f32x4;

// float -> bf16 (round-nearest-even)
__device__ inline short f2bf(float f) {
    unsigned u = __builtin_bit_cast(unsigned, f);
    unsigned r = u + 0x7fffu + ((u >> 16) & 1u);
    return (short)(r >> 16);
}

// Kernel 1, fused:
//   blocks [0,256):    h = x@W via MFMA (one head x 64 n-rows) -> hF in
//                      fragment order; e1/e2 stored as PRE-EXPONENTIATED
//                      float2 pairs {exp(e), exp(0.2*e)} so k2 needs no
//                      transcendentals. Also zeroes d_out.
//   blocks [256,1280): adj -> bitmask adjb (unchanged).
__global__ __launch_bounds__(256) void gat_k1(const float* __restrict__ x,
                                              const float* __restrict__ W,
                                              const float* __restrict__ a,
                                              const int* __restrict__ adj,
                                              short* __restrict__ hF,
                                              float2* __restrict__ e1f,
                                              float2* __restrict__ e2f,
                                              unsigned* __restrict__ adjb,
                                              float* __restrict__ out) {
    __shared__ __align__(16) short xs[64][XPITCH];    // 34.0 KB
    __shared__ __align__(16) short wts[64][XPITCH];   // 34.0 KB
    __shared__ __align__(16) short hbuf[64][HPITCH];  //  9.5 KB
    const int t    = threadIdx.x;
    const int bid  = blockIdx.x;
    const int lane = t & 63;
    const int w    = t >> 6;

    if (bid >= 256) {
        // ---- adj bitmask pack ----
        const int row = (bid - 256) * 4 + w;
        const int4* arow4 = (const int4*)(adj + (size_t)row * N);
        unsigned* drow = adjb + (size_t)row * 128;
        #pragma unroll
        for (int p4 = 0; p4 < 4; ++p4) {
            int4 ca[4];
            #pragma unroll
            for (int k = 0; k < 4; ++k)
                ca[k] = arow4[(p4 * 4 + k) * 64 + lane];   // batched, coalesced 1KB
            #pragma unroll
            for (int k = 0; k < 4; ++k) {
                const int4 v = ca[k];
                unsigned n = (v.x != 0 ? 1u : 0u) | (v.y != 0 ? 2u : 0u) |
                             (v.z != 0 ? 4u : 0u) | (v.w != 0 ? 8u : 0u);
                unsigned b  = n   | ((unsigned)__shfl_xor((int)n,   1, 64) << 4);
                unsigned hw = b   | ((unsigned)__shfl_xor((int)b,   2, 64) << 8);
                unsigned d  = hw  | ((unsigned)__shfl_xor((int)hw,  4, 64) << 16);
                if ((lane & 7) == 0) drow[(p4 * 4 + k) * 8 + (lane >> 3)] = d;
            }
        }
        return;
    }

    // ---- GEMM block ----
    ((float4*)out)[bid * 256 + t] = make_float4(0.f, 0.f, 0.f, 0.f);

    const int hd = bid >> 6;
    const int n0 = (bid & 63) * 64;
    const int c0 = hd * 64;

    {   // stage x rows n0..n0+63 as bf16
        const float4* xsrc = (const float4*)(x + (size_t)n0 * FIN);
        #pragma unroll
        for (int it = 0; it < 16; ++it) {
            const int fi = it * 256 + t;
            const float4 v = xsrc[fi];
            short4 o;
            o.x = f2bf(v.x); o.y = f2bf(v.y); o.z = f2bf(v.z); o.w = f2bf(v.w);
            *(short4*)&xs[fi >> 6][(fi & 63) * 4] = o;
        }
    }
    {   // stage W^T column slice
        const int c  = t & 63;
        const int k4 = (t >> 6) * 4;
        #pragma unroll
        for (int it = 0; it < 16; ++it) {
            const int k = it * 16 + k4;
            short4 pk;
            pk.x = f2bf(W[(k + 0) * CC + c0 + c]);
            pk.y = f2bf(W[(k + 1) * CC + c0 + c]);
            pk.z = f2bf(W[(k + 2) * CC + c0 + c]);
            pk.w = f2bf(W[(k + 3) * CC + c0 + c]);
            *(short4*)&wts[c][k] = pk;
        }
    }
    __syncthreads();

    const int m = lane & 15;
    const int q = lane >> 4;

    f32x4 acc[4];
    #pragma unroll
    for (int ct = 0; ct < 4; ++ct) acc[ct] = (f32x4){0.f, 0.f, 0.f, 0.f};

    #pragma unroll
    for (int ks = 0; ks < 8; ++ks) {
        const bf16x8 af = *(const bf16x8*)&xs[w * 16 + m][ks * 32 + q * 8];
        #pragma unroll
        for (int ct = 0; ct < 4; ++ct) {
            const bf16x8 bf_ = *(const bf16x8*)&wts[ct * 16 + m][ks * 32 + q * 8];
            acc[ct] = __builtin_amdgcn_mfma_f32_16x16x32_bf16(af, bf_, acc[ct], 0, 0, 0);
        }
    }

    // e1/e2 from fp32 acc (C layout: row=q*4+r, col=ct*16+m)
    const float a1v[4] = {a[m], a[16 + m], a[32 + m], a[48 + m]};
    const float a2v[4] = {a[64 + m], a[80 + m], a[96 + m], a[112 + m]};
    #pragma unroll
    for (int r = 0; r < 4; ++r) {
        float s1 = 0.f, s2 = 0.f;
        #pragma unroll
        for (int ct = 0; ct < 4; ++ct) {
            s1 = fmaf(acc[ct][r], a1v[ct], s1);
            s2 = fmaf(acc[ct][r], a2v[ct], s2);
        }
        #pragma unroll
        for (int sh = 1; sh < 16; sh <<= 1) {
            s1 += __shfl_xor(s1, sh, 64);
            s2 += __shfl_xor(s2, sh, 64);
        }
        if (m == 0) {
            const int n = n0 + w * 16 + q * 4 + r;
            e1f[(size_t)hd * N + n] = make_float2(__expf(s1), __expf(0.2f * s1));
            e2f[(size_t)hd * N + n] = make_float2(__expf(s2), __expf(0.2f * s2));
        }
    }

    // transpose h tile to hbuf[c][n-local]
    #pragma unroll
    for (int ct = 0; ct < 4; ++ct)
        #pragma unroll
        for (int r = 0; r < 4; ++r)
            hbuf[ct * 16 + m][w * 16 + q * 4 + r] = f2bf(acc[ct][r]);
    __syncthreads();

    // write hF in fragment order: frag(jc, ft) lane lp holds
    // h[f=ft*16+(lp&15)][j = jc*32 + (lp>>4)*8 + 0..7]
    {
        const int lp = t & 63;
        const int ft = t >> 6;
        const int mm = lp & 15;
        const int qq = lp >> 4;
        #pragma unroll
        for (int c2 = 0; c2 < 2; ++c2) {
            const bf16x8 hv = *(const bf16x8*)&hbuf[ft * 16 + mm][c2 * 32 + qq * 8];
            const size_t jc = (size_t)(n0 >> 5) + c2;
            *(bf16x8*)(hF + ((((size_t)hd * 128 + jc) * 4 + ft) * 64 + lp) * 8) = hv;
        }
    }
}

// Kernel 2: masked-softmax aggregation via MFMA.
// Restructured for occupancy: 16 i-rows per block, grid 1024 (4 blocks/CU),
// 8 j-stripe waves, VGPR-capped to 64 -> 32 waves/CU (2x the old design).
// No exp in the inner loop: w = max(E1p*E2p, E1n*E2n)  (== exp(leakyrelu(e))).
// e2 pairs and adj bytes read straight from L2 (no LDS staging);
// LDS is just obuf (pitch 66, 2-way-free atomics) + zbuf = 4.7 KB.
__global__ __launch_bounds__(512, 8) void gat_k2(const short* __restrict__ hF,
                                                 const unsigned* __restrict__ adjb,
                                                 const float2* __restrict__ e1f,
                                                 const float2* __restrict__ e2f,
                                                 float* __restrict__ out) {
    __shared__ float obuf[16][66];            // 4.125 KB, pitch 66 dw
    __shared__ float zbuf[8][16];             // 0.5 KB
    const int t    = threadIdx.x;
    const int lane = t & 63;
    const int g    = t >> 6;                  // j-stripe wave 0..7
    const int bid  = blockIdx.x;
    const int hd   = (bid >> 3) & 3;
    const int it   = (bid & 7) | ((bid >> 5) << 3);   // XCD-affine i-tile
    const int i0   = it * 16;
    const int m    = lane & 15;
    const int q    = lane >> 4;

    // zero numerator buffer (16*66 = 1056 floats)
    {
        float* ob = &obuf[0][0];
        if (t < 528) { ob[t] = 0.f; ob[t + 528] = 0.f; }
    }

    const float2 E1 = e1f[(size_t)hd * N + i0 + m];   // {exp(e1), exp(0.2 e1)}

    f32x4 acc[4];
    #pragma unroll
    for (int ft = 0; ft < 4; ++ft) acc[ft] = (f32x4){0.f, 0.f, 0.f, 0.f};
    float zacc = 0.f;

    const short* hbase = hF + (((size_t)hd * 128 + g) * 4 * 64 + lane) * 8;
    const unsigned char* ab =
        ((const unsigned char*)adjb) + (size_t)(i0 + m) * 512 + g * 4 + q;
    const float4* e2p4 = (const float4*)(e2f + (size_t)hd * N);

    #pragma unroll 2
    for (int step = 0; step < 16; ++step) {
        const short* hstep = hbase + (size_t)step * 16384;   // 8 chunks * 2048
        const bf16x8 b0 = *(const bf16x8*)(hstep);
        const bf16x8 b1 = *(const bf16x8*)(hstep + 512);
        const bf16x8 b2 = *(const bf16x8*)(hstep + 1024);
        const bf16x8 b3 = *(const bf16x8*)(hstep + 1536);

        const int jb = g * 32 + step * 256 + q * 8;   // this lane's first j
        const float4 c0 = e2p4[(jb >> 1) + 0];        // {E2p,E2n} for j, j+1
        const float4 c1 = e2p4[(jb >> 1) + 1];
        const float4 c2 = e2p4[(jb >> 1) + 2];
        const float4 c3 = e2p4[(jb >> 1) + 3];
        const unsigned bits = (unsigned)ab[step * 32];

        const float ep[8] = {c0.x, c0.z, c1.x, c1.z, c2.x, c2.z, c3.x, c3.z};
        const float en[8] = {c0.y, c0.w, c1.y, c1.w, c2.y, c2.w, c3.y, c3.w};

        bf16x8 af;
        #pragma unroll
        for (int jj = 0; jj < 8; ++jj) {
            // sign-mask from adjacency bit jj: 0 or 0xFFFFFFFF (v_bfe_i32)
            const unsigned msk = (unsigned)(((int)(bits << (31 - jj))) >> 31);
            float wv = fmaxf(E1.x * ep[jj], E1.y * en[jj]);  // exp(leakyrelu)
            wv = __builtin_bit_cast(float, __builtin_bit_cast(unsigned, wv) & msk);
            zacc += wv;
            af[jj] = f2bf(wv);
        }

        acc[0] = __builtin_amdgcn_mfma_f32_16x16x32_bf16(af, b0, acc[0], 0, 0, 0);
        acc[1] = __builtin_amdgcn_mfma_f32_16x16x32_bf16(af, b1, acc[1], 0, 0, 0);
        acc[2] = __builtin_amdgcn_mfma_f32_16x16x32_bf16(af, b2, acc[2], 0, 0, 0);
        acc[3] = __builtin_amdgcn_mfma_f32_16x16x32_bf16(af, b3, acc[3], 0, 0, 0);
    }

    // Z: stripe partial per row (sum over q groups)
    zacc += __shfl_xor(zacc, 16, 64);
    zacc += __shfl_xor(zacc, 32, 64);
    if (lane < 16) zbuf[g][lane] = zacc;

    __syncthreads();   // obuf zero + zbuf visible

    // numerator merge: C layout row=q*4+r, col=ft*16+m; pitch-66 -> 2-way free
    #pragma unroll
    for (int ft = 0; ft < 4; ++ft)
        #pragma unroll
        for (int r = 0; r < 4; ++r)
            atomicAdd(&obuf[q * 4 + r][ft * 16 + m], acc[ft][r]);
    __syncthreads();

    #pragma unroll
    for (int rep = 0; rep < 2; ++rep) {
        const int idx = t + rep * 512;
        const int ii  = idx >> 6;     // 0..15
        const int ff  = idx & 63;
        float Z = 0.f;
        #pragma unroll
        for (int gg = 0; gg < 8; ++gg) Z += zbuf[gg][ii];
        atomicAdd(&out[(size_t)(i0 + ii) * FOUT + ff], 0.25f * obuf[ii][ff] / Z);
    }
}

extern "C" void kernel_launch(void* const* d_in, const int* in_sizes, int n_in,
                              void* d_out, int out_size, void* d_ws, size_t ws_size,
                              hipStream_t stream) {
    const float* x   = (const float*)d_in[0];
    const int*   adj = (const int*)d_in[1];
    const float* W   = (const float*)d_in[2];
    const float* a   = (const float*)d_in[3];
    float* out = (float*)d_out;

    short*    hF   = (short*)d_ws;                            // 2 MB
    float2*   e1f  = (float2*)(hF + (size_t)HEADS * FOUT * N);// 128 KB
    float2*   e2f  = e1f + (size_t)HEADS * N;                 // 128 KB
    unsigned* adjb = (unsigned*)(e2f + (size_t)HEADS * N);    // 2 MB

    gat_k1<<<1280, 256, 0, stream>>>(x, W, a, adj, hF, e1f, e2f, adjb, out);
    gat_k2<<<1024, 512, 0, stream>>>(hF, adjb, e1f, e2f, out);
}

// Round 2
// 168.029 us; speedup vs baseline: 1.1309x; 1.1309x over previous
//
#include <hip/hip_runtime.h>

#define N     4096
#define FIN   256
#define CC    256   // HEADS * F_OUT
#define HEADS 4
#define FOUT  64
#define XPITCH 266  // FIN+10 shorts = 133 dwords (odd) -> conflict-free
#define HPITCH 74   // 37 dwords (odd)

typedef __attribute__((ext_vector_type(8))) short bf16x8;
typedef __attribute__((ext_vector_type(4))) float f32x4;

// float -> bf16 (round-nearest-even)
__device__ inline short f2bf(float f) {
    unsigned u = __builtin_bit_cast(unsigned, f);
    unsigned r = u + 0x7fffu + ((u >> 16) & 1u);
    return (short)(r >> 16);
}

// Kernel 1, fused:
//   blocks [0,256):    h = x@W via MFMA (one head x 64 n-rows) -> hF in
//                      fragment order; e1/e2 stored as PRE-EXPONENTIATED
//                      float2 pairs {exp(e), exp(0.2*e)} so k2 needs no
//                      transcendentals. Also zeroes d_out.
//   blocks [256,1280): adj -> bitmask adjb. One row per wave, batched int4
//                      loads, nibble/byte/hword shfl_xor packing.
__global__ __launch_bounds__(256) void gat_k1(const float* __restrict__ x,
                                              const float* __restrict__ W,
                                              const float* __restrict__ a,
                                              const int* __restrict__ adj,
                                              short* __restrict__ hF,
                                              float2* __restrict__ e1f,
                                              float2* __restrict__ e2f,
                                              unsigned* __restrict__ adjb,
                                              float* __restrict__ out) {
    __shared__ __align__(16) short xs[64][XPITCH];    // 34.0 KB
    __shared__ __align__(16) short wts[64][XPITCH];   // 34.0 KB
    __shared__ __align__(16) short hbuf[64][HPITCH];  //  9.5 KB
    const int t    = threadIdx.x;
    const int bid  = blockIdx.x;
    const int lane = t & 63;
    const int w    = t >> 6;

    if (bid >= 256) {
        // ---- adj bitmask pack ----
        const int row = (bid - 256) * 4 + w;
        const int4* arow4 = (const int4*)(adj + (size_t)row * N);
        unsigned* drow = adjb + (size_t)row * 128;
        #pragma unroll
        for (int p4 = 0; p4 < 4; ++p4) {
            int4 ca[4];
            #pragma unroll
            for (int k = 0; k < 4; ++k)
                ca[k] = arow4[(p4 * 4 + k) * 64 + lane];   // batched, coalesced 1KB
            #pragma unroll
            for (int k = 0; k < 4; ++k) {
                const int4 v = ca[k];
                unsigned n = (v.x != 0 ? 1u : 0u) | (v.y != 0 ? 2u : 0u) |
                             (v.z != 0 ? 4u : 0u) | (v.w != 0 ? 8u : 0u);
                unsigned b  = n   | ((unsigned)__shfl_xor((int)n,   1, 64) << 4);
                unsigned hw = b   | ((unsigned)__shfl_xor((int)b,   2, 64) << 8);
                unsigned d  = hw  | ((unsigned)__shfl_xor((int)hw,  4, 64) << 16);
                if ((lane & 7) == 0) drow[(p4 * 4 + k) * 8 + (lane >> 3)] = d;
            }
        }
        return;
    }

    // ---- GEMM block ----
    ((float4*)out)[bid * 256 + t] = make_float4(0.f, 0.f, 0.f, 0.f);

    const int hd = bid >> 6;
    const int n0 = (bid & 63) * 64;
    const int c0 = hd * 64;

    {   // stage x rows n0..n0+63 as bf16
        const float4* xsrc = (const float4*)(x + (size_t)n0 * FIN);
        #pragma unroll
        for (int it = 0; it < 16; ++it) {
            const int fi = it * 256 + t;
            const float4 v = xsrc[fi];
            short4 o;
            o.x = f2bf(v.x); o.y = f2bf(v.y); o.z = f2bf(v.z); o.w = f2bf(v.w);
            *(short4*)&xs[fi >> 6][(fi & 63) * 4] = o;
        }
    }
    {   // stage W^T column slice
        const int c  = t & 63;
        const int k4 = (t >> 6) * 4;
        #pragma unroll
        for (int it = 0; it < 16; ++it) {
            const int k = it * 16 + k4;
            short4 pk;
            pk.x = f2bf(W[(k + 0) * CC + c0 + c]);
            pk.y = f2bf(W[(k + 1) * CC + c0 + c]);
            pk.z = f2bf(W[(k + 2) * CC + c0 + c]);
            pk.w = f2bf(W[(k + 3) * CC + c0 + c]);
            *(short4*)&wts[c][k] = pk;
        }
    }
    __syncthreads();

    const int m = lane & 15;
    const int q = lane >> 4;

    f32x4 acc[4];
    #pragma unroll
    for (int ct = 0; ct < 4; ++ct) acc[ct] = (f32x4){0.f, 0.f, 0.f, 0.f};

    #pragma unroll
    for (int ks = 0; ks < 8; ++ks) {
        const bf16x8 af = *(const bf16x8*)&xs[w * 16 + m][ks * 32 + q * 8];
        #pragma unroll
        for (int ct = 0; ct < 4; ++ct) {
            const bf16x8 bf_ = *(const bf16x8*)&wts[ct * 16 + m][ks * 32 + q * 8];
            acc[ct] = __builtin_amdgcn_mfma_f32_16x16x32_bf16(af, bf_, acc[ct], 0, 0, 0);
        }
    }

    // e1/e2 from fp32 acc (C layout: row=q*4+r, col=ct*16+m)
    const float a1v[4] = {a[m], a[16 + m], a[32 + m], a[48 + m]};
    const float a2v[4] = {a[64 + m], a[80 + m], a[96 + m], a[112 + m]};
    #pragma unroll
    for (int r = 0; r < 4; ++r) {
        float s1 = 0.f, s2 = 0.f;
        #pragma unroll
        for (int ct = 0; ct < 4; ++ct) {
            s1 = fmaf(acc[ct][r], a1v[ct], s1);
            s2 = fmaf(acc[ct][r], a2v[ct], s2);
        }
        #pragma unroll
        for (int sh = 1; sh < 16; sh <<= 1) {
            s1 += __shfl_xor(s1, sh, 64);
            s2 += __shfl_xor(s2, sh, 64);
        }
        if (m == 0) {
            const int n = n0 + w * 16 + q * 4 + r;
            e1f[(size_t)hd * N + n] = make_float2(__expf(s1), __expf(0.2f * s1));
            e2f[(size_t)hd * N + n] = make_float2(__expf(s2), __expf(0.2f * s2));
        }
    }

    // transpose h tile to hbuf[c][n-local]
    #pragma unroll
    for (int ct = 0; ct < 4; ++ct)
        #pragma unroll
        for (int r = 0; r < 4; ++r)
            hbuf[ct * 16 + m][w * 16 + q * 4 + r] = f2bf(acc[ct][r]);
    __syncthreads();

    // write hF in fragment order: frag(jc, ft) lane lp holds
    // h[f=ft*16+(lp&15)][j = jc*32 + (lp>>4)*8 + 0..7]
    {
        const int lp = t & 63;
        const int ft = t >> 6;
        const int mm = lp & 15;
        const int qq = lp >> 4;
        #pragma unroll
        for (int c2 = 0; c2 < 2; ++c2) {
            const bf16x8 hv = *(const bf16x8*)&hbuf[ft * 16 + mm][c2 * 32 + qq * 8];
            const size_t jc = (size_t)(n0 >> 5) + c2;
            *(bf16x8*)(hF + ((((size_t)hd * 128 + jc) * 4 + ft) * 64 + lp) * 8) = hv;
        }
    }
}

// Kernel 2: masked-softmax aggregation via MFMA, 32 i-rows per block
// (2 A-frags share each B-frag -> hF L2 traffic halved). One head per
// block; 8 waves = 8 j-stripes (Z completes in-block). Grid 512 = 2/CU.
// vs round 0: (a) no exp in inner loop -- weights come from precomputed
// {exp(e), exp(0.2e)} pairs, w = max(E1p*E2p, E1n*E2n) & adjmask;
// (b) manual 1-deep software pipeline of the hF B-fragment loads so L2/L3
// latency hides under the weight-VALU block.
__global__ __launch_bounds__(512, 4) void gat_k2(const short* __restrict__ hF,
                                                 const unsigned* __restrict__ adjb,
                                                 const float2* __restrict__ e1f,
                                                 const float2* __restrict__ e2f,
                                                 float* __restrict__ out) {
    __shared__ float obuf[32][64];            //  8 KB
    __shared__ float zbuf[8][32];             //  1 KB
    __shared__ __align__(16) float e2lds[2 * N];  // 32 KB: {p,n} pairs
    __shared__ unsigned adjlds[32 * 129];     // 16.5 KB (129-dw pitch, odd)
    const int t    = threadIdx.x;
    const int lane = t & 63;
    const int g    = t >> 6;
    const int bid  = blockIdx.x;
    const int hd   = (bid >> 3) & 3;
    const int it   = (bid & 7) | ((bid >> 5) << 3);   // XCD-affine i-tile
    const int i0   = it * 32;
    const int m    = lane & 15;
    const int q    = lane >> 4;

    {   // zero numerator
        float* ob = &obuf[0][0];
        #pragma unroll
        for (int r = 0; r < 4; ++r) ob[t + r * 512] = 0.f;
    }
    {   // stage e2 pairs (this head, all j): 2048 float4
        const float4* src = (const float4*)(e2f + (size_t)hd * N);
        float4* dst = (float4*)e2lds;
        #pragma unroll
        for (int r = 0; r < 4; ++r) dst[t + r * 512] = src[t + r * 512];
    }
    {   // stage adj bits for 32 i-rows
        const unsigned* src = adjb + (size_t)i0 * 128;
        #pragma unroll
        for (int r = 0; r < 8; ++r) {
            const int idx = t + r * 512;
            adjlds[(idx >> 7) * 129 + (idx & 127)] = src[idx];
        }
    }
    __syncthreads();

    const float2 E1a = e1f[(size_t)hd * N + i0 + m];        // {exp, exp0.2}
    const float2 E1b = e1f[(size_t)hd * N + i0 + 16 + m];

    f32x4 accf[4], accg[4];
    #pragma unroll
    for (int ft = 0; ft < 4; ++ft) {
        accf[ft] = (f32x4){0.f, 0.f, 0.f, 0.f};
        accg[ft] = (f32x4){0.f, 0.f, 0.f, 0.f};
    }
    float zacc0 = 0.f, zacc1 = 0.f;

    const short* hbase = hF + (((size_t)hd * 128 + g) * 4 * 64 + lane) * 8;
    const unsigned char* abyte0 = ((const unsigned char*)adjlds) + m * 516 + g * 4 + q;
    const unsigned char* abyte1 = abyte0 + 16 * 516;

    // prologue: load step-0 B-fragments
    bf16x8 b0 = *(const bf16x8*)(hbase);
    bf16x8 b1 = *(const bf16x8*)(hbase + 512);
    bf16x8 b2 = *(const bf16x8*)(hbase + 1024);
    bf16x8 b3 = *(const bf16x8*)(hbase + 1536);

    for (int step = 0; step < 16; ++step) {
        // issue NEXT step's B-fragment loads first (wrap: step 15 reloads
        // step 0 -- L2 hit, unused; avoids a branch)
        const short* hn = hbase + (size_t)((step + 1) & 15) * 16384;
        const bf16x8 n0 = *(const bf16x8*)(hn);
        const bf16x8 n1 = *(const bf16x8*)(hn + 512);
        const bf16x8 n2 = *(const bf16x8*)(hn + 1024);
        const bf16x8 n3 = *(const bf16x8*)(hn + 1536);

        const int jb = g * 32 + step * 256 + q * 8;   // first j of this lane
        const float4* e2v = (const float4*)&e2lds[2 * jb];
        const float4 d0 = e2v[0];
        const float4 d1 = e2v[1];
        const float4 d2 = e2v[2];
        const float4 d3 = e2v[3];
        const unsigned bits0 = (unsigned)abyte0[step * 32];
        const unsigned bits1 = (unsigned)abyte1[step * 32];

        const float ep[8] = {d0.x, d0.z, d1.x, d1.z, d2.x, d2.z, d3.x, d3.z};
        const float en[8] = {d0.y, d0.w, d1.y, d1.w, d2.y, d2.w, d3.y, d3.w};

        bf16x8 af0, af1;
        #pragma unroll
        for (int jj = 0; jj < 8; ++jj) {
            // sign-mask from adjacency bit jj: 0 or 0xFFFFFFFF
            const unsigned mska = (unsigned)(((int)(bits0 << (31 - jj))) >> 31);
            const unsigned mskb = (unsigned)(((int)(bits1 << (31 - jj))) >> 31);
            float wa = fmaxf(E1a.x * ep[jj], E1a.y * en[jj]);  // exp(leakyrelu)
            float wb = fmaxf(E1b.x * ep[jj], E1b.y * en[jj]);
            wa = __builtin_bit_cast(float, __builtin_bit_cast(unsigned, wa) & mska);
            wb = __builtin_bit_cast(float, __builtin_bit_cast(unsigned, wb) & mskb);
            zacc0 += wa; zacc1 += wb;
            af0[jj] = f2bf(wa);
            af1[jj] = f2bf(wb);
        }

        accf[0] = __builtin_amdgcn_mfma_f32_16x16x32_bf16(af0, b0, accf[0], 0, 0, 0);
        accg[0] = __builtin_amdgcn_mfma_f32_16x16x32_bf16(af1, b0, accg[0], 0, 0, 0);
        accf[1] = __builtin_amdgcn_mfma_f32_16x16x32_bf16(af0, b1, accf[1], 0, 0, 0);
        accg[1] = __builtin_amdgcn_mfma_f32_16x16x32_bf16(af1, b1, accg[1], 0, 0, 0);
        accf[2] = __builtin_amdgcn_mfma_f32_16x16x32_bf16(af0, b2, accf[2], 0, 0, 0);
        accg[2] = __builtin_amdgcn_mfma_f32_16x16x32_bf16(af1, b2, accg[2], 0, 0, 0);
        accf[3] = __builtin_amdgcn_mfma_f32_16x16x32_bf16(af0, b3, accf[3], 0, 0, 0);
        accg[3] = __builtin_amdgcn_mfma_f32_16x16x32_bf16(af1, b3, accg[3], 0, 0, 0);

        b0 = n0; b1 = n1; b2 = n2; b3 = n3;
    }

    // Z: stripe partial per row
    zacc0 += __shfl_xor(zacc0, 16, 64);
    zacc0 += __shfl_xor(zacc0, 32, 64);
    zacc1 += __shfl_xor(zacc1, 16, 64);
    zacc1 += __shfl_xor(zacc1, 32, 64);
    if (lane < 16) {
        zbuf[g][lane]      = zacc0;
        zbuf[g][16 + lane] = zacc1;
    }

    // numerator: C layout row=q*4+r, col=ft*16+m
    #pragma unroll
    for (int ft = 0; ft < 4; ++ft)
        #pragma unroll
        for (int r = 0; r < 4; ++r) {
            atomicAdd(&obuf[q * 4 + r][ft * 16 + m], accf[ft][r]);
            atomicAdd(&obuf[16 + q * 4 + r][ft * 16 + m], accg[ft][r]);
        }
    __syncthreads();

    #pragma unroll
    for (int rep = 0; rep < 4; ++rep) {
        const int idx = t + rep * 512;
        const int ii  = idx >> 6;     // 0..31
        const int ff  = idx & 63;
        float Z = 0.f;
        #pragma unroll
        for (int gg = 0; gg < 8; ++gg) Z += zbuf[gg][ii];
        atomicAdd(&out[(size_t)(i0 + ii) * FOUT + ff], 0.25f * obuf[ii][ff] / Z);
    }
}

extern "C" void kernel_launch(void* const* d_in, const int* in_sizes, int n_in,
                              void* d_out, int out_size, void* d_ws, size_t ws_size,
                              hipStream_t stream) {
    const float* x   = (const float*)d_in[0];
    const int*   adj = (const int*)d_in[1];
    const float* W   = (const float*)d_in[2];
    const float* a   = (const float*)d_in[3];
    float* out = (float*)d_out;

    short*    hF   = (short*)d_ws;                            // 2 MB
    float2*   e1f  = (float2*)(hF + (size_t)HEADS * FOUT * N);// 128 KB
    float2*   e2f  = e1f + (size_t)HEADS * N;                 // 128 KB
    unsigned* adjb = (unsigned*)(e2f + (size_t)HEADS * N);    // 2 MB

    gat_k1<<<1280, 256, 0, stream>>>(x, W, a, adj, hF, e1f, e2f, adjb, out);
    gat_k2<<<512, 512, 0, stream>>>(hF, adjb, e1f, e2f, out);
}

// Round 3
// 155.521 us; speedup vs baseline: 1.2219x; 1.0804x over previous
//
#include <hip/hip_runtime.h>

#define N     4096
#define FIN   256
#define CC    256   // HEADS * F_OUT
#define HEADS 4
#define FOUT  64
#define XPITCH 266  // FIN+10 shorts = 133 dwords (odd) -> conflict-free

typedef __attribute__((ext_vector_type(8))) short bf16x8;
typedef __attribute__((ext_vector_type(4))) float f32x4;

// float -> bf16 (round-nearest-even)
__device__ inline short f2bf(float f) {
    unsigned u = __builtin_bit_cast(unsigned, f);
    unsigned r = u + 0x7fffu + ((u >> 16) & 1u);
    return (short)(r >> 16);
}

// ---------------------------------------------------------------------------
// k1a: h = x@W via MFMA (one head x 64 n-rows per block, grid 256) -> hF in
// fragment order; e1/e2 stored PRE-EXPONENTIATED as {exp(e), exp(0.2e)}.
// Also zeroes d_out (k2b accumulates into it atomically).
// ---------------------------------------------------------------------------
__global__ __launch_bounds__(256) void gat_k1a(const float* __restrict__ x,
                                               const float* __restrict__ W,
                                               const float* __restrict__ a,
                                               short* __restrict__ hF,
                                               float2* __restrict__ e1f,
                                               float2* __restrict__ e2f,
                                               float* __restrict__ out) {
    __shared__ __align__(16) short xs[64][XPITCH];    // 34.0 KB
    __shared__ __align__(16) short wts[64][XPITCH];   // 34.0 KB
    __shared__ __align__(16) short hbuf[64][74];      //  9.5 KB
    const int t    = threadIdx.x;
    const int bid  = blockIdx.x;
    const int lane = t & 63;
    const int w    = t >> 6;

    ((float4*)out)[bid * 256 + t] = make_float4(0.f, 0.f, 0.f, 0.f);

    const int hd = bid >> 6;
    const int n0 = (bid & 63) * 64;
    const int c0 = hd * 64;

    {   // stage x rows n0..n0+63 as bf16
        const float4* xsrc = (const float4*)(x + (size_t)n0 * FIN);
        #pragma unroll
        for (int it = 0; it < 16; ++it) {
            const int fi = it * 256 + t;
            const float4 v = xsrc[fi];
            short4 o;
            o.x = f2bf(v.x); o.y = f2bf(v.y); o.z = f2bf(v.z); o.w = f2bf(v.w);
            *(short4*)&xs[fi >> 6][(fi & 63) * 4] = o;
        }
    }
    {   // stage W^T column slice
        const int c  = t & 63;
        const int k4 = (t >> 6) * 4;
        #pragma unroll
        for (int it = 0; it < 16; ++it) {
            const int k = it * 16 + k4;
            short4 pk;
            pk.x = f2bf(W[(k + 0) * CC + c0 + c]);
            pk.y = f2bf(W[(k + 1) * CC + c0 + c]);
            pk.z = f2bf(W[(k + 2) * CC + c0 + c]);
            pk.w = f2bf(W[(k + 3) * CC + c0 + c]);
            *(short4*)&wts[c][k] = pk;
        }
    }
    __syncthreads();

    const int m = lane & 15;
    const int q = lane >> 4;

    f32x4 acc[4];
    #pragma unroll
    for (int ct = 0; ct < 4; ++ct) acc[ct] = (f32x4){0.f, 0.f, 0.f, 0.f};

    #pragma unroll
    for (int ks = 0; ks < 8; ++ks) {
        const bf16x8 af = *(const bf16x8*)&xs[w * 16 + m][ks * 32 + q * 8];
        #pragma unroll
        for (int ct = 0; ct < 4; ++ct) {
            const bf16x8 bf_ = *(const bf16x8*)&wts[ct * 16 + m][ks * 32 + q * 8];
            acc[ct] = __builtin_amdgcn_mfma_f32_16x16x32_bf16(af, bf_, acc[ct], 0, 0, 0);
        }
    }

    // e1/e2 from fp32 acc (C layout: row=q*4+r, col=ct*16+m)
    const float a1v[4] = {a[m], a[16 + m], a[32 + m], a[48 + m]};
    const float a2v[4] = {a[64 + m], a[80 + m], a[96 + m], a[112 + m]};
    #pragma unroll
    for (int r = 0; r < 4; ++r) {
        float s1 = 0.f, s2 = 0.f;
        #pragma unroll
        for (int ct = 0; ct < 4; ++ct) {
            s1 = fmaf(acc[ct][r], a1v[ct], s1);
            s2 = fmaf(acc[ct][r], a2v[ct], s2);
        }
        #pragma unroll
        for (int sh = 1; sh < 16; sh <<= 1) {
            s1 += __shfl_xor(s1, sh, 64);
            s2 += __shfl_xor(s2, sh, 64);
        }
        if (m == 0) {
            const int n = n0 + w * 16 + q * 4 + r;
            e1f[(size_t)hd * N + n] = make_float2(__expf(s1), __expf(0.2f * s1));
            e2f[(size_t)hd * N + n] = make_float2(__expf(s2), __expf(0.2f * s2));
        }
    }

    // transpose h tile to hbuf[c][n-local]
    #pragma unroll
    for (int ct = 0; ct < 4; ++ct)
        #pragma unroll
        for (int r = 0; r < 4; ++r)
            hbuf[ct * 16 + m][w * 16 + q * 4 + r] = f2bf(acc[ct][r]);
    __syncthreads();

    // write hF in fragment order: frag(jc32, ft) lane lp holds
    // h[f=ft*16+(lp&15)][j = jc32*32 + (lp>>4)*8 + 0..7]
    {
        const int lp = t & 63;
        const int ft = t >> 6;
        const int mm = lp & 15;
        const int qq = lp >> 4;
        #pragma unroll
        for (int c2 = 0; c2 < 2; ++c2) {
            const bf16x8 hv = *(const bf16x8*)&hbuf[ft * 16 + mm][c2 * 32 + qq * 8];
            const size_t jc = (size_t)(n0 >> 5) + c2;
            *(bf16x8*)(hF + ((((size_t)hd * 128 + jc) * 4 + ft) * 64 + lp) * 8) = hv;
        }
    }
}

// ---------------------------------------------------------------------------
// k1b: adj -> bitmask. ZERO LDS (the old fused version reserved 77.5 KB and
// capped the 64 MB stream at 2 blocks/CU). Grid 2048 x 256: wave = half-row,
// 8 batched int4 loads (8 KB in flight/wave), then nibble/byte/hword
// shfl_xor packing. Same adjb layout as before (little-endian bit order).
// ---------------------------------------------------------------------------
__global__ __launch_bounds__(256) void gat_k1b(const int* __restrict__ adj,
                                               unsigned* __restrict__ adjb) {
    const int t    = threadIdx.x;
    const int lane = t & 63;
    const int w    = t >> 6;
    const int row  = blockIdx.x * 2 + (w >> 1);
    const int half = w & 1;
    const int4* arow4 = (const int4*)(adj + (size_t)row * N) + half * 512;
    unsigned*   drow  = adjb + (size_t)row * 128 + half * 64;

    int4 ca[8];
    #pragma unroll
    for (int k = 0; k < 8; ++k)
        ca[k] = arow4[k * 64 + lane];          // batched: 8 KB in flight
    #pragma unroll
    for (int k = 0; k < 8; ++k) {
        const int4 v = ca[k];
        unsigned n = (v.x != 0 ? 1u : 0u) | (v.y != 0 ? 2u : 0u) |
                     (v.z != 0 ? 4u : 0u) | (v.w != 0 ? 8u : 0u);
        unsigned b  = n   | ((unsigned)__shfl_xor((int)n,   1, 64) << 4);
        unsigned hw = b   | ((unsigned)__shfl_xor((int)b,   2, 64) << 8);
        unsigned d  = hw  | ((unsigned)__shfl_xor((int)hw,  4, 64) << 16);
        if ((lane & 7) == 0) drow[k * 8 + (lane >> 3)] = d;
    }
}

// ---------------------------------------------------------------------------
// k2a: Z-pass. Z[h][i] = sum_j adj(i,j) * max(E1p*E2p, E1n*E2n).
// Block = (head, 8 rows); head's e2 pairs staged once in LDS (32 KB),
// shared by 8 row-waves. Grid 2048 x 512. One plain store per row.
// ---------------------------------------------------------------------------
__global__ __launch_bounds__(512) void gat_k2a(const float2* __restrict__ e1f,
                                               const float2* __restrict__ e2f,
                                               const unsigned* __restrict__ adjb,
                                               float* __restrict__ Zg) {
    __shared__ __align__(16) float e2s[2 * N];   // 32 KB
    const int t    = threadIdx.x;
    const int lane = t & 63;
    const int g    = t >> 6;
    const int bid  = blockIdx.x;
    const int hd   = bid >> 9;
    const int row  = (bid & 511) * 8 + g;

    {
        const float4* s = (const float4*)(e2f + (size_t)hd * N);
        float4* d = (float4*)e2s;
        #pragma unroll
        for (int r = 0; r < 4; ++r) d[t + r * 512] = s[t + r * 512];
    }
    __syncthreads();

    const float2 E1 = e1f[(size_t)hd * N + row];
    const unsigned* ar = adjb + (size_t)row * 128;
    float z = 0.f;
    #pragma unroll 4
    for (int k = 0; k < 64; ++k) {
        const int j = k * 64 + lane;
        const float2 p = ((const float2*)e2s)[j];
        const unsigned bd  = ar[(unsigned)j >> 5];
        const unsigned msk = 0u - ((bd >> (lane & 31)) & 1u);
        float wv = fmaxf(E1.x * p.x, E1.y * p.y);   // exp(leakyrelu(e1+e2))
        wv = __builtin_bit_cast(float, __builtin_bit_cast(unsigned, wv) & msk);
        z += wv;
    }
    #pragma unroll
    for (int sh = 1; sh < 64; sh <<= 1) z += __shfl_xor(z, sh, 64);
    if (lane == 0) Zg[(size_t)hd * N + row] = z;
}

// ---------------------------------------------------------------------------
// k2b: numerator via MFMA with hF SHARED across waves (the 4x traffic cut).
// Block = (head, 128 i-rows, 1024-j chunk); 8 waves own 16 i-rows each and
// consume the SAME B-frags, double-buffer-staged in LDS (K=64 macrosteps,
// issue-early/write-late). 0.25/Z folded into E1 -> normalization free; acc
// goes straight to out via atomics (16 contributors per cell: 4 hd x 4 jc).
// Grid 512 (2 blocks/CU), LDS 42 KB, VGPR target <=128.
// ---------------------------------------------------------------------------
__global__ __launch_bounds__(512, 4) void gat_k2b(const short* __restrict__ hF,
                                                  const unsigned* __restrict__ adjb,
                                                  const float2* __restrict__ e1f,
                                                  const float2* __restrict__ e2f,
                                                  const float* __restrict__ Zg,
                                                  float* __restrict__ out) {
    __shared__ __align__(16) short    hstage[2][4096];  // 2 x 8 KB
    __shared__ __align__(16) float    e2s[2048];        // 8 KB (1024 pairs)
    __shared__ __align__(16) unsigned adjl[128 * 36];   // 18 KB, pitch 36 dw
    const int t    = threadIdx.x;
    const int lane = t & 63;
    const int g    = t >> 6;
    const int bid  = blockIdx.x;
    const int xcd  = bid & 7;
    const int idx  = bid >> 3;
    const int hd   = idx & 3;
    const int jc   = (idx >> 2) & 3;
    const int it   = xcd | ((idx >> 4) << 3);   // XCD-affine i-tile
    const int i0   = it * 128;
    const int j0   = jc * 1024;
    const int m    = lane & 15;
    const int q    = lane >> 4;

    // stage e2 slice (1024 pairs)
    ((float4*)e2s)[t] = ((const float4*)(e2f + (size_t)hd * N + j0))[t];
    // stage adj slice: 128 rows x 32 dwords (this jc), pitch 36 (16B-aligned,
    // 2-way-free on the per-step byte read)
    {
        const int row = t >> 2, part = t & 3;
        const uint4* src = (const uint4*)(adjb + (size_t)(i0 + row) * 128 + jc * 32 + part * 8);
        uint4* dst = (uint4*)(adjl + row * 36 + part * 8);
        dst[0] = src[0];
        dst[1] = src[1];
    }
    // prologue: stage macro 0 of hF (8 KB = 512 x uint4)
    const uint4* gsrc = (const uint4*)(hF + ((size_t)hd * 128 + jc * 32) * 2048);
    ((uint4*)hstage[0])[t] = gsrc[t];
    __syncthreads();

    const int   rowi = i0 + g * 16 + m;
    const float2 E1r = e1f[(size_t)hd * N + rowi];
    const float  zs  = 0.25f / Zg[(size_t)hd * N + rowi];
    const float  E1x = E1r.x * zs;
    const float  E1y = E1r.y * zs;

    f32x4 acc[4];
    #pragma unroll
    for (int ft = 0; ft < 4; ++ft) acc[ft] = (f32x4){0.f, 0.f, 0.f, 0.f};

    const unsigned char* ab = ((const unsigned char*)adjl) + (g * 16 + m) * 144 + q;

    int cur = 0;
    #pragma unroll 2
    for (int mac = 0; mac < 16; ++mac) {
        // issue next macro's global loads FIRST (latency hides under compute)
        const uint4 v = gsrc[(size_t)((mac + 1) & 15) * 512 + t];

        const short* hb = &hstage[cur][0];
        #pragma unroll
        for (int s = 0; s < 2; ++s) {
            const int jloc = mac * 64 + s * 32 + q * 8;
            const bf16x8 b0 = *(const bf16x8*)(hb + s * 2048 + 0 * 512 + lane * 8);
            const bf16x8 b1 = *(const bf16x8*)(hb + s * 2048 + 1 * 512 + lane * 8);
            const bf16x8 b2 = *(const bf16x8*)(hb + s * 2048 + 2 * 512 + lane * 8);
            const bf16x8 b3 = *(const bf16x8*)(hb + s * 2048 + 3 * 512 + lane * 8);
            const float4* ev = (const float4*)&e2s[2 * jloc];
            const float4 d0 = ev[0], d1 = ev[1], d2 = ev[2], d3 = ev[3];
            const unsigned bits = (unsigned)ab[(mac * 2 + s) * 4];

            const float ep[8] = {d0.x, d0.z, d1.x, d1.z, d2.x, d2.z, d3.x, d3.z};
            const float en[8] = {d0.y, d0.w, d1.y, d1.w, d2.y, d2.w, d3.y, d3.w};

            bf16x8 af;
            #pragma unroll
            for (int jj = 0; jj < 8; ++jj) {
                const unsigned msk = (unsigned)(((int)(bits << (31 - jj))) >> 31);
                float wv = fmaxf(E1x * ep[jj], E1y * en[jj]);  // 0.25*exp(lrelu)/Z
                wv = __builtin_bit_cast(float, __builtin_bit_cast(unsigned, wv) & msk);
                af[jj] = f2bf(wv);
            }

            acc[0] = __builtin_amdgcn_mfma_f32_16x16x32_bf16(af, b0, acc[0], 0, 0, 0);
            acc[1] = __builtin_amdgcn_mfma_f32_16x16x32_bf16(af, b1, acc[1], 0, 0, 0);
            acc[2] = __builtin_amdgcn_mfma_f32_16x16x32_bf16(af, b2, acc[2], 0, 0, 0);
            acc[3] = __builtin_amdgcn_mfma_f32_16x16x32_bf16(af, b3, acc[3], 0, 0, 0);
        }

        if (mac < 15) {
            ((uint4*)hstage[cur ^ 1])[t] = v;   // write-late (stalls only on vmcnt)
            __syncthreads();
            cur ^= 1;
        }
    }

    // epilogue: C layout row=q*4+r (within wave's 16 rows), col=ft*16+m
    #pragma unroll
    for (int ft = 0; ft < 4; ++ft)
        #pragma unroll
        for (int r = 0; r < 4; ++r)
            atomicAdd(&out[(size_t)(i0 + g * 16 + q * 4 + r) * FOUT + ft * 16 + m],
                      acc[ft][r]);
}

extern "C" void kernel_launch(void* const* d_in, const int* in_sizes, int n_in,
                              void* d_out, int out_size, void* d_ws, size_t ws_size,
                              hipStream_t stream) {
    const float* x   = (const float*)d_in[0];
    const int*   adj = (const int*)d_in[1];
    const float* W   = (const float*)d_in[2];
    const float* a   = (const float*)d_in[3];
    float* out = (float*)d_out;

    short*    hF   = (short*)d_ws;                            // 2 MB
    float2*   e1f  = (float2*)(hF + (size_t)HEADS * FOUT * N);// 128 KB
    float2*   e2f  = e1f + (size_t)HEADS * N;                 // 128 KB
    unsigned* adjb = (unsigned*)(e2f + (size_t)HEADS * N);    // 2 MB
    float*    Zg   = (float*)(adjb + (size_t)N * 128);        // 64 KB

    gat_k1a<<<256, 256, 0, stream>>>(x, W, a, hF, e1f, e2f, out);
    gat_k1b<<<2048, 256, 0, stream>>>(adj, adjb);
    gat_k2a<<<2048, 512, 0, stream>>>(e1f, e2f, adjb, Zg);
    gat_k2b<<<512, 512, 0, stream>>>(hF, adjb, e1f, e2f, Zg, out);
}

// Round 4
// 136.012 us; speedup vs baseline: 1.3971x; 1.1434x over previous
//
#include <hip/hip_runtime.h>

#define N     4096
#define FIN   256
#define CC    256   // HEADS * F_OUT
#define HEADS 4
#define FOUT  64
#define XPITCH 266  // FIN+10 shorts = 133 dwords (odd) -> conflict-free

typedef __attribute__((ext_vector_type(8))) short bf16x8;
typedef __attribute__((ext_vector_type(4))) float f32x4;

// float -> bf16 (round-nearest-even)
__device__ inline short f2bf(float f) {
    unsigned u = __builtin_bit_cast(unsigned, f);
    unsigned r = u + 0x7fffu + ((u >> 16) & 1u);
    return (short)(r >> 16);
}

// ---------------------------------------------------------------------------
// k1a: h = x@W via MFMA (one head x 64 n-rows per block, grid 256) -> hF in
// fragment order; e1/e2 stored PRE-EXPONENTIATED as {exp(e), exp(0.2e)}.
// 512 threads (8 waves/CU): all waves stage + write hF, waves 0-3 compute
// (MFMA+e phase is ~1us; staging latency was the cost at 4 waves/CU).
// No out-zeroing anymore (k3 plain-stores the full output).
// ---------------------------------------------------------------------------
__global__ __launch_bounds__(512) void gat_k1a(const float* __restrict__ x,
                                               const float* __restrict__ W,
                                               const float* __restrict__ a,
                                               short* __restrict__ hF,
                                               float2* __restrict__ e1f,
                                               float2* __restrict__ e2f) {
    __shared__ __align__(16) short xs[64][XPITCH];    // 34.0 KB
    __shared__ __align__(16) short wts[64][XPITCH];   // 34.0 KB
    __shared__ __align__(16) short hbuf[64][74];      //  9.5 KB
    const int t    = threadIdx.x;
    const int bid  = blockIdx.x;
    const int lane = t & 63;
    const int w    = t >> 6;          // 0..7

    const int hd = bid >> 6;
    const int n0 = (bid & 63) * 64;
    const int c0 = hd * 64;

    {   // stage x rows n0..n0+63 as bf16 (4096 float4 over 512 threads)
        const float4* xsrc = (const float4*)(x + (size_t)n0 * FIN);
        #pragma unroll
        for (int it = 0; it < 8; ++it) {
            const int fi = it * 512 + t;
            const float4 v = xsrc[fi];
            short4 o;
            o.x = f2bf(v.x); o.y = f2bf(v.y); o.z = f2bf(v.z); o.w = f2bf(v.w);
            *(short4*)&xs[fi >> 6][(fi & 63) * 4] = o;
        }
    }
    {   // stage W^T column slice (coalesced across c)
        const int c  = t & 63;
        const int k4 = (t >> 6) * 4;  // 0..28 step 4
        #pragma unroll
        for (int it = 0; it < 8; ++it) {
            const int k = it * 32 + k4;
            short4 pk;
            pk.x = f2bf(W[(k + 0) * CC + c0 + c]);
            pk.y = f2bf(W[(k + 1) * CC + c0 + c]);
            pk.z = f2bf(W[(k + 2) * CC + c0 + c]);
            pk.w = f2bf(W[(k + 3) * CC + c0 + c]);
            *(short4*)&wts[c][k] = pk;
        }
    }
    __syncthreads();

    const int m = lane & 15;
    const int q = lane >> 4;

    if (w < 4) {   // compute waves: w = row-group
        f32x4 acc[4];
        #pragma unroll
        for (int ct = 0; ct < 4; ++ct) acc[ct] = (f32x4){0.f, 0.f, 0.f, 0.f};

        #pragma unroll
        for (int ks = 0; ks < 8; ++ks) {
            const bf16x8 af = *(const bf16x8*)&xs[w * 16 + m][ks * 32 + q * 8];
            #pragma unroll
            for (int ct = 0; ct < 4; ++ct) {
                const bf16x8 bf_ = *(const bf16x8*)&wts[ct * 16 + m][ks * 32 + q * 8];
                acc[ct] = __builtin_amdgcn_mfma_f32_16x16x32_bf16(af, bf_, acc[ct], 0, 0, 0);
            }
        }

        // e1/e2 from fp32 acc (C layout: row=q*4+r, col=ct*16+m)
        const float a1v[4] = {a[m], a[16 + m], a[32 + m], a[48 + m]};
        const float a2v[4] = {a[64 + m], a[80 + m], a[96 + m], a[112 + m]};
        #pragma unroll
        for (int r = 0; r < 4; ++r) {
            float s1 = 0.f, s2 = 0.f;
            #pragma unroll
            for (int ct = 0; ct < 4; ++ct) {
                s1 = fmaf(acc[ct][r], a1v[ct], s1);
                s2 = fmaf(acc[ct][r], a2v[ct], s2);
            }
            #pragma unroll
            for (int sh = 1; sh < 16; sh <<= 1) {
                s1 += __shfl_xor(s1, sh, 64);
                s2 += __shfl_xor(s2, sh, 64);
            }
            if (m == 0) {
                const int n = n0 + w * 16 + q * 4 + r;
                e1f[(size_t)hd * N + n] = make_float2(__expf(s1), __expf(0.2f * s1));
                e2f[(size_t)hd * N + n] = make_float2(__expf(s2), __expf(0.2f * s2));
            }
        }

        // transpose h tile to hbuf[c][n-local]
        #pragma unroll
        for (int ct = 0; ct < 4; ++ct)
            #pragma unroll
            for (int r = 0; r < 4; ++r)
                hbuf[ct * 16 + m][w * 16 + q * 4 + r] = f2bf(acc[ct][r]);
    }
    __syncthreads();

    // write hF in fragment order: frag(jc32, ft) lane lp holds
    // h[f=ft*16+(lp&15)][j = jc32*32 + (lp>>4)*8 + 0..7]; 512 threads -> one
    // (ft, c2) pair each.
    {
        const int lp = t & 63;
        const int ft = (t >> 6) & 3;
        const int c2 = t >> 8;
        const int mm = lp & 15;
        const int qq = lp >> 4;
        const bf16x8 hv = *(const bf16x8*)&hbuf[ft * 16 + mm][c2 * 32 + qq * 8];
        const size_t jc = (size_t)(n0 >> 5) + c2;
        *(bf16x8*)(hF + ((((size_t)hd * 128 + jc) * 4 + ft) * 64 + lp) * 8) = hv;
    }
}

// ---------------------------------------------------------------------------
// k1b: adj -> bitmask. Zero LDS, grid 2048 x 256 (full occupancy on the
// 64 MB stream). Wave = half-row, 8 batched int4 loads (8 KB in flight),
// nibble/byte/hword shfl_xor packing, little-endian bit order.
// ---------------------------------------------------------------------------
__global__ __launch_bounds__(256) void gat_k1b(const int* __restrict__ adj,
                                               unsigned* __restrict__ adjb) {
    const int t    = threadIdx.x;
    const int lane = t & 63;
    const int w    = t >> 6;
    const int row  = blockIdx.x * 2 + (w >> 1);
    const int half = w & 1;
    const int4* arow4 = (const int4*)(adj + (size_t)row * N) + half * 512;
    unsigned*   drow  = adjb + (size_t)row * 128 + half * 64;

    int4 ca[8];
    #pragma unroll
    for (int k = 0; k < 8; ++k)
        ca[k] = arow4[k * 64 + lane];          // batched: 8 KB in flight
    #pragma unroll
    for (int k = 0; k < 8; ++k) {
        const int4 v = ca[k];
        unsigned n = (v.x != 0 ? 1u : 0u) | (v.y != 0 ? 2u : 0u) |
                     (v.z != 0 ? 4u : 0u) | (v.w != 0 ? 8u : 0u);
        unsigned b  = n   | ((unsigned)__shfl_xor((int)n,   1, 64) << 4);
        unsigned hw = b   | ((unsigned)__shfl_xor((int)b,   2, 64) << 8);
        unsigned d  = hw  | ((unsigned)__shfl_xor((int)hw,  4, 64) << 16);
        if ((lane & 7) == 0) drow[k * 8 + (lane >> 3)] = d;
    }
}

// ---------------------------------------------------------------------------
// k2b: numerator + Z partials via MFMA, hF shared across 8 waves through an
// LDS double-buffer (K=64 macrosteps, issue-early/write-late). Block =
// (head, 128 i-rows, 1024-j chunk), grid 512 (2 blocks/CU).
// NO atomics: each block exclusively owns rows (i0..i0+127) of its (hd,jc)
// slice -> plain coalesced stores to num[hd][jc] and Zp[hd][jc]. k3 reduces.
// ---------------------------------------------------------------------------
__global__ __launch_bounds__(512, 4) void gat_k2b(const short* __restrict__ hF,
                                                  const unsigned* __restrict__ adjb,
                                                  const float2* __restrict__ e1f,
                                                  const float2* __restrict__ e2f,
                                                  float* __restrict__ num,
                                                  float* __restrict__ Zp) {
    __shared__ __align__(16) short    hstage[2][4096];  // 2 x 8 KB
    __shared__ __align__(16) float    e2s[2048];        // 8 KB (1024 pairs)
    __shared__ __align__(16) unsigned adjl[128 * 36];   // 18 KB, pitch 36 dw
    const int t    = threadIdx.x;
    const int lane = t & 63;
    const int g    = t >> 6;
    const int bid  = blockIdx.x;
    const int xcd  = bid & 7;
    const int idx  = bid >> 3;
    const int hd   = idx & 3;
    const int jc   = (idx >> 2) & 3;
    const int it   = xcd | ((idx >> 4) << 3);   // XCD-affine i-tile
    const int i0   = it * 128;
    const int j0   = jc * 1024;
    const int m    = lane & 15;
    const int q    = lane >> 4;
    const int slice = hd * 4 + jc;

    // stage e2 slice (1024 pairs)
    ((float4*)e2s)[t] = ((const float4*)(e2f + (size_t)hd * N + j0))[t];
    // stage adj slice: 128 rows x 32 dwords (this jc), pitch 36
    {
        const int row = t >> 2, part = t & 3;
        const uint4* src = (const uint4*)(adjb + (size_t)(i0 + row) * 128 + jc * 32 + part * 8);
        uint4* dst = (uint4*)(adjl + row * 36 + part * 8);
        dst[0] = src[0];
        dst[1] = src[1];
    }
    // prologue: stage macro 0 of hF (8 KB = 512 x uint4)
    const uint4* gsrc = (const uint4*)(hF + ((size_t)hd * 128 + jc * 32) * 2048);
    ((uint4*)hstage[0])[t] = gsrc[t];
    __syncthreads();

    const int    rowi = i0 + g * 16 + m;
    const float2 E1r  = e1f[(size_t)hd * N + rowi];
    const float  E1x  = E1r.x;
    const float  E1y  = E1r.y;

    f32x4 acc[4];
    #pragma unroll
    for (int ft = 0; ft < 4; ++ft) acc[ft] = (f32x4){0.f, 0.f, 0.f, 0.f};
    float zacc = 0.f;

    const unsigned char* ab = ((const unsigned char*)adjl) + (g * 16 + m) * 144 + q;

    int cur = 0;
    #pragma unroll 2
    for (int mac = 0; mac < 16; ++mac) {
        // issue next macro's global loads FIRST (latency hides under compute)
        const uint4 v = gsrc[(size_t)((mac + 1) & 15) * 512 + t];

        const short* hb = &hstage[cur][0];
        #pragma unroll
        for (int s = 0; s < 2; ++s) {
            const int jloc = mac * 64 + s * 32 + q * 8;
            const bf16x8 b0 = *(const bf16x8*)(hb + s * 2048 + 0 * 512 + lane * 8);
            const bf16x8 b1 = *(const bf16x8*)(hb + s * 2048 + 1 * 512 + lane * 8);
            const bf16x8 b2 = *(const bf16x8*)(hb + s * 2048 + 2 * 512 + lane * 8);
            const bf16x8 b3 = *(const bf16x8*)(hb + s * 2048 + 3 * 512 + lane * 8);
            const float4* ev = (const float4*)&e2s[2 * jloc];
            const float4 d0 = ev[0], d1 = ev[1], d2 = ev[2], d3 = ev[3];
            const unsigned bits = (unsigned)ab[(mac * 2 + s) * 4];

            const float ep[8] = {d0.x, d0.z, d1.x, d1.z, d2.x, d2.z, d3.x, d3.z};
            const float en[8] = {d0.y, d0.w, d1.y, d1.w, d2.y, d2.w, d3.y, d3.w};

            bf16x8 af;
            #pragma unroll
            for (int jj = 0; jj < 8; ++jj) {
                const unsigned msk = (unsigned)(((int)(bits << (31 - jj))) >> 31);
                float wv = fmaxf(E1x * ep[jj], E1y * en[jj]);  // exp(leakyrelu)
                wv = __builtin_bit_cast(float, __builtin_bit_cast(unsigned, wv) & msk);
                zacc += wv;
                af[jj] = f2bf(wv);
            }

            acc[0] = __builtin_amdgcn_mfma_f32_16x16x32_bf16(af, b0, acc[0], 0, 0, 0);
            acc[1] = __builtin_amdgcn_mfma_f32_16x16x32_bf16(af, b1, acc[1], 0, 0, 0);
            acc[2] = __builtin_amdgcn_mfma_f32_16x16x32_bf16(af, b2, acc[2], 0, 0, 0);
            acc[3] = __builtin_amdgcn_mfma_f32_16x16x32_bf16(af, b3, acc[3], 0, 0, 0);
        }

        if (mac < 15) {
            ((uint4*)hstage[cur ^ 1])[t] = v;   // write-late (stalls only on vmcnt)
            __syncthreads();
            cur ^= 1;
        }
    }

    // Z partial for this jc chunk: reduce over q, plain store (exclusive rows)
    zacc += __shfl_xor(zacc, 16, 64);
    zacc += __shfl_xor(zacc, 32, 64);
    if (lane < 16)
        Zp[(size_t)slice * N + i0 + g * 16 + lane] = zacc;

    // numerator partial: C layout row=q*4+r, col=ft*16+m; plain stores
    {
        float* nrow = num + ((size_t)slice * N + i0 + g * 16) * FOUT;
        #pragma unroll
        for (int ft = 0; ft < 4; ++ft)
            #pragma unroll
            for (int r = 0; r < 4; ++r)
                nrow[(q * 4 + r) * FOUT + ft * 16 + m] = acc[ft][r];
    }
}

// ---------------------------------------------------------------------------
// k3: out[i][f] = 0.25 * sum_hd (sum_jc num[hd][jc][i][f]) / (sum_jc Zp[hd][jc][i])
// 256 blocks x 256 threads, float4 per thread; 17 MB read / 1 MB write.
// ---------------------------------------------------------------------------
__global__ __launch_bounds__(256) void gat_k3(const float* __restrict__ num,
                                              const float* __restrict__ Zp,
                                              float* __restrict__ out) {
    const int g4 = blockIdx.x * 256 + threadIdx.x;   // 0..65535
    const int i  = g4 >> 4;
    const int fo = (g4 & 15) * 4;
    float4 r = make_float4(0.f, 0.f, 0.f, 0.f);
    #pragma unroll
    for (int hd = 0; hd < 4; ++hd) {
        float4 s = make_float4(0.f, 0.f, 0.f, 0.f);
        float  z = 0.f;
        #pragma unroll
        for (int jc = 0; jc < 4; ++jc) {
            const int sl = hd * 4 + jc;
            const float4 v = *(const float4*)(num + ((size_t)sl * N + i) * FOUT + fo);
            s.x += v.x; s.y += v.y; s.z += v.z; s.w += v.w;
            z += Zp[(size_t)sl * N + i];
        }
        const float inv = 1.f / z;
        r.x += s.x * inv; r.y += s.y * inv; r.z += s.z * inv; r.w += s.w * inv;
    }
    r.x *= 0.25f; r.y *= 0.25f; r.z *= 0.25f; r.w *= 0.25f;
    *(float4*)(out + (size_t)i * FOUT + fo) = r;
}

extern "C" void kernel_launch(void* const* d_in, const int* in_sizes, int n_in,
                              void* d_out, int out_size, void* d_ws, size_t ws_size,
                              hipStream_t stream) {
    const float* x   = (const float*)d_in[0];
    const int*   adj = (const int*)d_in[1];
    const float* W   = (const float*)d_in[2];
    const float* a   = (const float*)d_in[3];
    float* out = (float*)d_out;

    short*    hF   = (short*)d_ws;                            // 2 MB
    float2*   e1f  = (float2*)(hF + (size_t)HEADS * FOUT * N);// 128 KB
    float2*   e2f  = e1f + (size_t)HEADS * N;                 // 128 KB
    unsigned* adjb = (unsigned*)(e2f + (size_t)HEADS * N);    // 2 MB
    float*    num  = (float*)(adjb + (size_t)N * 128);        // 16 MB
    float*    Zp   = num + (size_t)16 * N * FOUT;             // 256 KB

    gat_k1a<<<256, 512, 0, stream>>>(x, W, a, hF, e1f, e2f);
    gat_k1b<<<2048, 256, 0, stream>>>(adj, adjb);
    gat_k2b<<<512, 512, 0, stream>>>(hF, adjb, e1f, e2f, num, Zp);
    gat_k3<<<256, 256, 0, stream>>>(num, Zp, out);
}

// Round 5
// 132.605 us; speedup vs baseline: 1.4330x; 1.0257x over previous
//
#include <hip/hip_runtime.h>

#define N     4096
#define FIN   256
#define CC    256   // HEADS * F_OUT
#define HEADS 4
#define FOUT  64
#define XPITCH 266  // FIN+10 shorts = 133 dwords (odd) -> conflict-free

typedef __attribute__((ext_vector_type(8))) short bf16x8;
typedef __attribute__((ext_vector_type(4))) float f32x4;
typedef __attribute__((ext_vector_type(2))) float f32x2;

// packed f32->bf16 (RNE), one instr for two values
__device__ inline unsigned cvtpk(float lo, float hi) {
    unsigned r;
    asm("v_cvt_pk_bf16_f32 %0, %1, %2" : "=v"(r) : "v"(lo), "v"(hi));
    return r;
}
// dual-FP32 packed multiply (CDNA full-rate)
__device__ inline f32x2 pkmul(f32x2 a, f32x2 b) {
    f32x2 r;
    asm("v_pk_mul_f32 %0, %1, %2" : "=v"(r) : "v"(a), "v"(b));
    return r;
}

// ---------------------------------------------------------------------------
// k1a: h = x@W via MFMA (one head x 64 n-rows per block, grid 256) -> hF in
// fragment order; e1/e2 stored PRE-EXPONENTIATED as {exp(e), exp(0.2e)}.
// 512 threads; staging conversions use v_cvt_pk_bf16_f32 (half the VALU of
// the scalar f2bf path).
// ---------------------------------------------------------------------------
__global__ __launch_bounds__(512) void gat_k1a(const float* __restrict__ x,
                                               const float* __restrict__ W,
                                               const float* __restrict__ a,
                                               short* __restrict__ hF,
                                               float2* __restrict__ e1f,
                                               float2* __restrict__ e2f) {
    __shared__ __align__(16) short xs[64][XPITCH];    // 34.0 KB
    __shared__ __align__(16) short wts[64][XPITCH];   // 34.0 KB
    __shared__ __align__(16) short hbuf[64][74];      //  9.5 KB
    const int t    = threadIdx.x;
    const int bid  = blockIdx.x;
    const int lane = t & 63;
    const int w    = t >> 6;          // 0..7

    const int hd = bid >> 6;
    const int n0 = (bid & 63) * 64;
    const int c0 = hd * 64;

    {   // stage x rows n0..n0+63 as bf16 (4096 float4 over 512 threads)
        const float4* xsrc = (const float4*)(x + (size_t)n0 * FIN);
        #pragma unroll
        for (int it = 0; it < 8; ++it) {
            const int fi = it * 512 + t;
            const float4 v = xsrc[fi];
            uint2 o;
            o.x = cvtpk(v.x, v.y);
            o.y = cvtpk(v.z, v.w);
            *(uint2*)&xs[fi >> 6][(fi & 63) * 4] = o;
        }
    }
    {   // stage W^T column slice (coalesced across c)
        const int c  = t & 63;
        const int k4 = (t >> 6) * 4;  // 0..28 step 4
        #pragma unroll
        for (int it = 0; it < 8; ++it) {
            const int k = it * 32 + k4;
            const float w0 = W[(k + 0) * CC + c0 + c];
            const float w1 = W[(k + 1) * CC + c0 + c];
            const float w2 = W[(k + 2) * CC + c0 + c];
            const float w3 = W[(k + 3) * CC + c0 + c];
            uint2 o;
            o.x = cvtpk(w0, w1);
            o.y = cvtpk(w2, w3);
            *(uint2*)&wts[c][k] = o;
        }
    }
    __syncthreads();

    const int m = lane & 15;
    const int q = lane >> 4;

    if (w < 4) {   // compute waves: w = row-group
        f32x4 acc[4];
        #pragma unroll
        for (int ct = 0; ct < 4; ++ct) acc[ct] = (f32x4){0.f, 0.f, 0.f, 0.f};

        #pragma unroll
        for (int ks = 0; ks < 8; ++ks) {
            const bf16x8 af = *(const bf16x8*)&xs[w * 16 + m][ks * 32 + q * 8];
            #pragma unroll
            for (int ct = 0; ct < 4; ++ct) {
                const bf16x8 bf_ = *(const bf16x8*)&wts[ct * 16 + m][ks * 32 + q * 8];
                acc[ct] = __builtin_amdgcn_mfma_f32_16x16x32_bf16(af, bf_, acc[ct], 0, 0, 0);
            }
        }

        // e1/e2 from fp32 acc (C layout: row=q*4+r, col=ct*16+m)
        const float a1v[4] = {a[m], a[16 + m], a[32 + m], a[48 + m]};
        const float a2v[4] = {a[64 + m], a[80 + m], a[96 + m], a[112 + m]};
        #pragma unroll
        for (int r = 0; r < 4; ++r) {
            float s1 = 0.f, s2 = 0.f;
            #pragma unroll
            for (int ct = 0; ct < 4; ++ct) {
                s1 = fmaf(acc[ct][r], a1v[ct], s1);
                s2 = fmaf(acc[ct][r], a2v[ct], s2);
            }
            #pragma unroll
            for (int sh = 1; sh < 16; sh <<= 1) {
                s1 += __shfl_xor(s1, sh, 64);
                s2 += __shfl_xor(s2, sh, 64);
            }
            if (m == 0) {
                const int n = n0 + w * 16 + q * 4 + r;
                e1f[(size_t)hd * N + n] = make_float2(__expf(s1), __expf(0.2f * s1));
                e2f[(size_t)hd * N + n] = make_float2(__expf(s2), __expf(0.2f * s2));
            }
        }

        // transpose h tile to hbuf[c][n-local]: rows q*4..q*4+3 are
        // consecutive n-local -> two packed dword stores per ct
        #pragma unroll
        for (int ct = 0; ct < 4; ++ct) {
            const unsigned lo = cvtpk(acc[ct][0], acc[ct][1]);
            const unsigned hi = cvtpk(acc[ct][2], acc[ct][3]);
            unsigned* hp = (unsigned*)&hbuf[ct * 16 + m][w * 16 + q * 4];
            hp[0] = lo;
            hp[1] = hi;
        }
    }
    __syncthreads();

    // write hF in fragment order: frag(jc32, ft) lane lp holds
    // h[f=ft*16+(lp&15)][j = jc32*32 + (lp>>4)*8 + 0..7]; 512 threads -> one
    // (ft, c2) pair each.
    {
        const int lp = t & 63;
        const int ft = (t >> 6) & 3;
        const int c2 = t >> 8;
        const int mm = lp & 15;
        const int qq = lp >> 4;
        const bf16x8 hv = *(const bf16x8*)&hbuf[ft * 16 + mm][c2 * 32 + qq * 8];
        const size_t jc = (size_t)(n0 >> 5) + c2;
        *(bf16x8*)(hF + ((((size_t)hd * 128 + jc) * 4 + ft) * 64 + lp) * 8) = hv;
    }
}

// ---------------------------------------------------------------------------
// k1b: adj -> bitmask. Zero LDS, grid 2048 x 256 (full occupancy on the
// 64 MB stream). Wave = half-row, 8 batched int4 loads (8 KB in flight),
// nibble/byte/hword shfl_xor packing, little-endian bit order.
// ---------------------------------------------------------------------------
__global__ __launch_bounds__(256) void gat_k1b(const int* __restrict__ adj,
                                               unsigned* __restrict__ adjb) {
    const int t    = threadIdx.x;
    const int lane = t & 63;
    const int w    = t >> 6;
    const int row  = blockIdx.x * 2 + (w >> 1);
    const int half = w & 1;
    const int4* arow4 = (const int4*)(adj + (size_t)row * N) + half * 512;
    unsigned*   drow  = adjb + (size_t)row * 128 + half * 64;

    int4 ca[8];
    #pragma unroll
    for (int k = 0; k < 8; ++k)
        ca[k] = arow4[k * 64 + lane];          // batched: 8 KB in flight
    #pragma unroll
    for (int k = 0; k < 8; ++k) {
        const int4 v = ca[k];
        unsigned n = (v.x != 0 ? 1u : 0u) | (v.y != 0 ? 2u : 0u) |
                     (v.z != 0 ? 4u : 0u) | (v.w != 0 ? 8u : 0u);
        unsigned b  = n   | ((unsigned)__shfl_xor((int)n,   1, 64) << 4);
        unsigned hw = b   | ((unsigned)__shfl_xor((int)b,   2, 64) << 8);
        unsigned d  = hw  | ((unsigned)__shfl_xor((int)hw,  4, 64) << 16);
        if ((lane & 7) == 0) drow[k * 8 + (lane >> 3)] = d;
    }
}

// ---------------------------------------------------------------------------
// k2b: numerator + Z partials via MFMA, hF shared across 8 waves through an
// LDS double-buffer. VALU diet vs round 4 (~9.5 -> ~3 instr/edge):
//   - v_pk_mul_f32: {E1p*E2p, E1n*E2n} in one instr (e2s stores pairs)
//   - v_cvt_pk_bf16_f32: two weights -> one packed dword
//   - adjacency mask via 256-entry LDS table (4 v_and per 16 edges)
//   - Z via one extra MFMA against an all-ones B-frag (no per-edge add)
// Block = (head, 128 i-rows, 1024-j chunk), grid 512 (2 blocks/CU). Plain
// stores to exclusively-owned num/Zp rows; k3 reduces.
// ---------------------------------------------------------------------------
__global__ __launch_bounds__(512, 4) void gat_k2b(const short* __restrict__ hF,
                                                  const unsigned* __restrict__ adjb,
                                                  const float2* __restrict__ e1f,
                                                  const float2* __restrict__ e2f,
                                                  float* __restrict__ num,
                                                  float* __restrict__ Zp) {
    __shared__ __align__(16) short    hstage[2][4096];  // 2 x 8 KB
    __shared__ __align__(16) float    e2s[2048];        // 8 KB (1024 pairs)
    __shared__ __align__(16) unsigned adjl[128 * 36];   // 18 KB, pitch 36 dw
    __shared__ __align__(16) uint4    mtab[256];        // 4 KB mask table
    const int t    = threadIdx.x;
    const int lane = t & 63;
    const int g    = t >> 6;
    const int bid  = blockIdx.x;
    const int xcd  = bid & 7;
    const int idx  = bid >> 3;
    const int hd   = idx & 3;
    const int jc   = (idx >> 2) & 3;
    const int it   = xcd | ((idx >> 4) << 3);   // XCD-affine i-tile
    const int i0   = it * 128;
    const int j0   = jc * 1024;
    const int m    = lane & 15;
    const int q    = lane >> 4;
    const int slice = hd * 4 + jc;

    // stage e2 slice (1024 pairs)
    ((float4*)e2s)[t] = ((const float4*)(e2f + (size_t)hd * N + j0))[t];
    // stage adj slice: 128 rows x 32 dwords (this jc), pitch 36
    {
        const int row = t >> 2, part = t & 3;
        const uint4* src = (const uint4*)(adjb + (size_t)(i0 + row) * 128 + jc * 32 + part * 8);
        uint4* dst = (uint4*)(adjl + row * 36 + part * 8);
        dst[0] = src[0];
        dst[1] = src[1];
    }
    // mask table: byte b -> 4 dwords of per-bf16-slot 0xFFFF masks
    if (t < 256) {
        const unsigned b = t;
        uint4 e;
        e.x = ((b & 1u)   ? 0xFFFFu : 0u) | ((b & 2u)   ? 0xFFFF0000u : 0u);
        e.y = ((b & 4u)   ? 0xFFFFu : 0u) | ((b & 8u)   ? 0xFFFF0000u : 0u);
        e.z = ((b & 16u)  ? 0xFFFFu : 0u) | ((b & 32u)  ? 0xFFFF0000u : 0u);
        e.w = ((b & 64u)  ? 0xFFFFu : 0u) | ((b & 128u) ? 0xFFFF0000u : 0u);
        mtab[b] = e;
    }
    // prologue: stage macro 0 of hF (8 KB = 512 x uint4)
    const uint4* gsrc = (const uint4*)(hF + ((size_t)hd * 128 + jc * 32) * 2048);
    ((uint4*)hstage[0])[t] = gsrc[t];
    __syncthreads();

    const int    rowi = i0 + g * 16 + m;
    const float2 E1r  = e1f[(size_t)hd * N + rowi];
    const f32x2  E1pk = (f32x2){E1r.x, E1r.y};

    bf16x8 onesb;
    #pragma unroll
    for (int e = 0; e < 8; ++e) onesb[e] = (short)0x3F80;   // bf16(1.0)

    f32x4 acc[4];
    #pragma unroll
    for (int ft = 0; ft < 4; ++ft) acc[ft] = (f32x4){0.f, 0.f, 0.f, 0.f};
    f32x4 accz = (f32x4){0.f, 0.f, 0.f, 0.f};

    const unsigned char* ab = ((const unsigned char*)adjl) + (g * 16 + m) * 144 + q;

    int cur = 0;
    #pragma unroll 2
    for (int mac = 0; mac < 16; ++mac) {
        // issue next macro's global loads FIRST (latency hides under compute)
        const uint4 v = gsrc[(size_t)((mac + 1) & 15) * 512 + t];

        // hoist the dependent LDS chain (bits byte -> mask table row)
        const unsigned bits0 = (unsigned)ab[(mac * 2 + 0) * 4];
        const unsigned bits1 = (unsigned)ab[(mac * 2 + 1) * 4];
        const uint4 mk0 = mtab[bits0];
        const uint4 mk1 = mtab[bits1];

        const short* hb = &hstage[cur][0];
        #pragma unroll
        for (int s = 0; s < 2; ++s) {
            const int jloc = mac * 64 + s * 32 + q * 8;
            const bf16x8 b0 = *(const bf16x8*)(hb + s * 2048 + 0 * 512 + lane * 8);
            const bf16x8 b1 = *(const bf16x8*)(hb + s * 2048 + 1 * 512 + lane * 8);
            const bf16x8 b2 = *(const bf16x8*)(hb + s * 2048 + 2 * 512 + lane * 8);
            const bf16x8 b3 = *(const bf16x8*)(hb + s * 2048 + 3 * 512 + lane * 8);
            const float4* ev = (const float4*)&e2s[2 * jloc];
            const float4 d0 = ev[0], d1 = ev[1], d2 = ev[2], d3 = ev[3];
            const uint4 mk = s ? mk1 : mk0;

            const f32x2 p0 = pkmul(E1pk, (f32x2){d0.x, d0.y});
            const f32x2 p1 = pkmul(E1pk, (f32x2){d0.z, d0.w});
            const f32x2 p2 = pkmul(E1pk, (f32x2){d1.x, d1.y});
            const f32x2 p3 = pkmul(E1pk, (f32x2){d1.z, d1.w});
            const f32x2 p4 = pkmul(E1pk, (f32x2){d2.x, d2.y});
            const f32x2 p5 = pkmul(E1pk, (f32x2){d2.z, d2.w});
            const f32x2 p6 = pkmul(E1pk, (f32x2){d3.x, d3.y});
            const f32x2 p7 = pkmul(E1pk, (f32x2){d3.z, d3.w});

            uint4 afu;
            afu.x = cvtpk(fmaxf(p0[0], p0[1]), fmaxf(p1[0], p1[1])) & mk.x;
            afu.y = cvtpk(fmaxf(p2[0], p2[1]), fmaxf(p3[0], p3[1])) & mk.y;
            afu.z = cvtpk(fmaxf(p4[0], p4[1]), fmaxf(p5[0], p5[1])) & mk.z;
            afu.w = cvtpk(fmaxf(p6[0], p6[1]), fmaxf(p7[0], p7[1])) & mk.w;
            const bf16x8 af = __builtin_bit_cast(bf16x8, afu);

            acc[0] = __builtin_amdgcn_mfma_f32_16x16x32_bf16(af, b0, acc[0], 0, 0, 0);
            acc[1] = __builtin_amdgcn_mfma_f32_16x16x32_bf16(af, b1, acc[1], 0, 0, 0);
            acc[2] = __builtin_amdgcn_mfma_f32_16x16x32_bf16(af, b2, acc[2], 0, 0, 0);
            acc[3] = __builtin_amdgcn_mfma_f32_16x16x32_bf16(af, b3, acc[3], 0, 0, 0);
            accz   = __builtin_amdgcn_mfma_f32_16x16x32_bf16(af, onesb, accz, 0, 0, 0);
        }

        if (mac < 15) {
            ((uint4*)hstage[cur ^ 1])[t] = v;   // write-late (stalls only on vmcnt)
            __syncthreads();
            cur ^= 1;
        }
    }

    // Z partials: accz lane (m,q) reg r = sum of masked quantized weights for
    // row q*4+r (all cols equal) -> store from m==0 lanes
    if (m == 0) {
        #pragma unroll
        for (int r = 0; r < 4; ++r)
            Zp[(size_t)slice * N + i0 + g * 16 + q * 4 + r] = accz[r];
    }

    // numerator partial: C layout row=q*4+r, col=ft*16+m; plain stores
    {
        float* nrow = num + ((size_t)slice * N + i0 + g * 16) * FOUT;
        #pragma unroll
        for (int ft = 0; ft < 4; ++ft)
            #pragma unroll
            for (int r = 0; r < 4; ++r)
                nrow[(q * 4 + r) * FOUT + ft * 16 + m] = acc[ft][r];
    }
}

// ---------------------------------------------------------------------------
// k3: out[i][f] = 0.25 * sum_hd (sum_jc num[hd][jc][i][f]) / (sum_jc Zp[hd][jc][i])
// 256 blocks x 256 threads, float4 per thread; 17 MB read / 1 MB write.
// ---------------------------------------------------------------------------
__global__ __launch_bounds__(256) void gat_k3(const float* __restrict__ num,
                                              const float* __restrict__ Zp,
                                              float* __restrict__ out) {
    const int g4 = blockIdx.x * 256 + threadIdx.x;   // 0..65535
    const int i  = g4 >> 4;
    const int fo = (g4 & 15) * 4;
    float4 r = make_float4(0.f, 0.f, 0.f, 0.f);
    #pragma unroll
    for (int hd = 0; hd < 4; ++hd) {
        float4 s = make_float4(0.f, 0.f, 0.f, 0.f);
        float  z = 0.f;
        #pragma unroll
        for (int jc = 0; jc < 4; ++jc) {
            const int sl = hd * 4 + jc;
            const float4 v = *(const float4*)(num + ((size_t)sl * N + i) * FOUT + fo);
            s.x += v.x; s.y += v.y; s.z += v.z; s.w += v.w;
            z += Zp[(size_t)sl * N + i];
        }
        const float inv = 1.f / z;
        r.x += s.x * inv; r.y += s.y * inv; r.z += s.z * inv; r.w += s.w * inv;
    }
    r.x *= 0.25f; r.y *= 0.25f; r.z *= 0.25f; r.w *= 0.25f;
    *(float4*)(out + (size_t)i * FOUT + fo) = r;
}

extern "C" void kernel_launch(void* const* d_in, const int* in_sizes, int n_in,
                              void* d_out, int out_size, void* d_ws, size_t ws_size,
                              hipStream_t stream) {
    const float* x   = (const float*)d_in[0];
    const int*   adj = (const int*)d_in[1];
    const float* W   = (const float*)d_in[2];
    const float* a   = (const float*)d_in[3];
    float* out = (float*)d_out;

    short*    hF   = (short*)d_ws;                            // 2 MB
    float2*   e1f  = (float2*)(hF + (size_t)HEADS * FOUT * N);// 128 KB
    float2*   e2f  = e1f + (size_t)HEADS * N;                 // 128 KB
    unsigned* adjb = (unsigned*)(e2f + (size_t)HEADS * N);    // 2 MB
    float*    num  = (float*)(adjb + (size_t)N * 128);        // 16 MB
    float*    Zp   = num + (size_t)16 * N * FOUT;             // 256 KB

    gat_k1a<<<256, 512, 0, stream>>>(x, W, a, hF, e1f, e2f);
    gat_k1b<<<2048, 256, 0, stream>>>(adj, adjb);
    gat_k2b<<<512, 512, 0, stream>>>(hF, adjb, e1f, e2f, num, Zp);
    gat_k3<<<256, 256, 0, stream>>>(num, Zp, out);
}